// Round 2
// baseline (873.111 us; speedup 1.0000x reference)
//
#include <hip/hip_runtime.h>
#include <hip/hip_bf16.h>

#define N_NODES  100000
#define N_EDGES  3200000
#define IN_FEAT  512
#define HIDDEN   64
#define N_GRAPHS 2048
#define CAP      96        // padded CSR row capacity; max in-degree ~ Poisson(32), max ~60 over 100K nodes

typedef __attribute__((ext_vector_type(8))) short short8;
typedef __attribute__((ext_vector_type(4))) float floatx4;

// RNE fp32 -> bf16 hi + bf16 lo split (hi+lo captures ~16 mantissa bits)
__device__ inline void bf16_split(float f, short& hi, short& lo) {
    unsigned u = __float_as_uint(f);
    unsigned r = (u + 0x7fffu + ((u >> 16) & 1u)) >> 16;     // RNE to bf16
    float fh = __uint_as_float(r << 16);
    float fl = f - fh;                                        // exact
    unsigned v = __float_as_uint(fl);
    unsigned s = (v + 0x7fffu + ((v >> 16) & 1u)) >> 16;
    hi = (short)r;
    lo = (short)s;
}

// ---------------------------------------------------------------- fused init
// pooled = 0; degi = 1 (self-loop); cntg via binary search on SORTED batch
__global__ __launch_bounds__(256) void fused_init(float* __restrict__ pooled,
                                                  int* __restrict__ degi,
                                                  int* __restrict__ cntg,
                                                  const int* __restrict__ batch,
                                                  int n, int g) {
    int i = blockIdx.x * 256 + threadIdx.x;      // grid covers g*64 >= n
    if (i < g * 64) pooled[i] = 0.f;
    if (i < n) degi[i] = 1;
    if (i < g) {
        int lo0 = 0, hi0 = n;
        while (lo0 < hi0) { int m = (lo0 + hi0) >> 1; if (batch[m] < i) lo0 = m + 1; else hi0 = m; }
        int lo1 = lo0, hi1 = n;
        while (lo1 < hi1) { int m = (lo1 + hi1) >> 1; if (batch[m] < i + 1) lo1 = m + 1; else hi1 = m; }
        cntg[i] = lo1 - lo0;
    }
}

// ---------------------------------------------------------------- W pre-split
// W[k][64] fp32 -> hi_t/lo_t[col][K] bf16 (transposed: GEMM staging = contiguous short8)
__global__ __launch_bounds__(256) void split_w(const float* __restrict__ W,
                                               short* __restrict__ hi_t,
                                               short* __restrict__ lo_t, int K) {
    int i = blockIdx.x * 256 + threadIdx.x;       // i = k*64 + c
    if (i < K * 64) {
        int k = i >> 6, c = i & 63;
        short h, l;
        bf16_split(W[i], h, l);
        hi_t[c * K + k] = h;
        lo_t[c * K + k] = l;
    }
}

// ---------------------------------------------------------------- single-pass padded-CSR build
// Replaces deg_rank + scan x3 + csr_scatter: one edge pass, atomic gives both
// the degree and the slot. Row n occupies csr_pad[n*CAP .. n*CAP+deg-1].
__global__ __launch_bounds__(256) void deg_scatter(const int* __restrict__ src,
                                                   const int* __restrict__ dst,
                                                   int* __restrict__ degi,
                                                   int* __restrict__ csr_pad, int e) {
    int i = (blockIdx.x * 256 + threadIdx.x) * 4;
    if (i + 4 <= e) {
        int4 d = *(const int4*)(dst + i);
        int4 s = *(const int4*)(src + i);
        int r;
        r = atomicAdd(&degi[d.x], 1) - 1; if (r < CAP) csr_pad[d.x * CAP + r] = s.x;
        r = atomicAdd(&degi[d.y], 1) - 1; if (r < CAP) csr_pad[d.y * CAP + r] = s.y;
        r = atomicAdd(&degi[d.z], 1) - 1; if (r < CAP) csr_pad[d.z * CAP + r] = s.z;
        r = atomicAdd(&degi[d.w], 1) - 1; if (r < CAP) csr_pad[d.w * CAP + r] = s.w;
    } else {
        for (int j = i; j < e; j++) {
            int r = atomicAdd(&degi[dst[j]], 1) - 1;
            if (r < CAP) csr_pad[dst[j] * CAP + r] = src[j];
        }
    }
}

// ---------------------------------------------------------------- split-bf16 MFMA GEMM
// Y[n,64] = dinv[n] * (X[n,K] @ W[K,64]); W pre-split (transposed [col][K]).
// dinv computed inline from degi: identical expression everywhere -> identical values.
template <int K>
__global__ __launch_bounds__(256) void gemm_mfma(const float* __restrict__ X,
                                                 const short* __restrict__ Whi,
                                                 const short* __restrict__ Wlo,
                                                 const int* __restrict__ degi,
                                                 float* __restrict__ Y, int nrows) {
    constexpr int BSTR = 40;                   // 32 + 8 pad: bank-conflict-free reads
    __shared__ short bhi[64 * BSTR];
    __shared__ short blo[64 * BSTR];

    const int t    = threadIdx.x;
    const int wave = t >> 6;
    const int lane = t & 63;
    const int quad = lane >> 4;
    const int l16  = lane & 15;

    const int arow   = blockIdx.x * 64 + wave * 16 + l16;
    const bool rvalid = arow < nrows;
    const float* xrow = X + (size_t)arow * K;

    const int scol = t & 63;
    const int skg  = t >> 6;
    const short* whp = Whi + (size_t)scol * K + skg * 8;
    const short* wlp = Wlo + (size_t)scol * K + skg * 8;

    floatx4 acc[4] = {};

#pragma unroll 1
    for (int k0 = 0; k0 < K; k0 += 32) {
        short8 whi = *(const short8*)(whp + k0);
        short8 wlo = *(const short8*)(wlp + k0);

        float av[8] = {0.f, 0.f, 0.f, 0.f, 0.f, 0.f, 0.f, 0.f};
        if (rvalid) {
            float4 p0 = *(const float4*)(xrow + k0 + quad * 8);
            float4 p1 = *(const float4*)(xrow + k0 + quad * 8 + 4);
            av[0] = p0.x; av[1] = p0.y; av[2] = p0.z; av[3] = p0.w;
            av[4] = p1.x; av[5] = p1.y; av[6] = p1.z; av[7] = p1.w;
        }
        short8 ahi, alo;
#pragma unroll
        for (int j = 0; j < 8; j++) { short h, l; bf16_split(av[j], h, l); ahi[j] = h; alo[j] = l; }

        __syncthreads();   // prior chunk's B reads complete before overwrite
        *(short8*)&bhi[scol * BSTR + skg * 8] = whi;
        *(short8*)&blo[scol * BSTR + skg * 8] = wlo;
        __syncthreads();   // B staged

#pragma unroll
        for (int ct = 0; ct < 4; ct++) {
            int col = ct * 16 + l16;
            short8 bh = *(short8*)&bhi[col * BSTR + quad * 8];
            short8 bl = *(short8*)&blo[col * BSTR + quad * 8];
            acc[ct] = __builtin_amdgcn_mfma_f32_16x16x32_bf16(ahi, bh, acc[ct], 0, 0, 0);
            acc[ct] = __builtin_amdgcn_mfma_f32_16x16x32_bf16(ahi, bl, acc[ct], 0, 0, 0);
            acc[ct] = __builtin_amdgcn_mfma_f32_16x16x32_bf16(alo, bh, acc[ct], 0, 0, 0);
        }
    }

    // C/D layout: col = ct*16 + l16, row = wave*16 + quad*4 + r
#pragma unroll
    for (int r = 0; r < 4; r++) {
        int orow = blockIdx.x * 64 + wave * 16 + quad * 4 + r;
        if (orow < nrows) {
            float dv = 1.0f / sqrtf((float)degi[orow]);
#pragma unroll
            for (int ct = 0; ct < 4; ct++)
                Y[(size_t)orow * 64 + ct * 16 + l16] = acc[ct][r] * dv;
        }
    }
}

// ---------------------------------------------------------------- GCN gather
// wave per node; lane = fg (0..15, feature group of 4) + 16*es (0..3 edge slot).
// Depth-4 inner loop (round-0 form): VGPR 28, occupancy ~75% — the gather is
// miss-service-throughput-bound, deeper unroll only costs occupancy (round 1).
template <bool RELU, bool POOL>
__global__ __launch_bounds__(256) void gcn_gather(const float* __restrict__ g,
                                                  const int* __restrict__ degi,
                                                  const int* __restrict__ csr_pad,
                                                  const float* __restrict__ bias,
                                                  float* __restrict__ out,
                                                  float* __restrict__ pooled,
                                                  const int* __restrict__ batch, int n) {
    int node = (blockIdx.x * 256 + threadIdx.x) >> 6;
    int lane = threadIdx.x & 63;
    int es = lane >> 4;
    int fg = lane & 15;
    if (node >= n) return;

    int dg = degi[node];
    int de = min(dg - 1, CAP);                  // edges stored for this row
    float dn = 1.0f / sqrtf((float)dg);
    int start = node * CAP;

    float4 a0 = make_float4(0.f, 0.f, 0.f, 0.f);
    float4 a1 = a0, a2 = a0, a3 = a0;
    if (es == 0) a0 = *(const float4*)(g + (size_t)node * 64 + fg * 4);  // self-loop

    for (int c = 0; c < de; c += 64) {
        int m = min(64, de - c);
        int sv = (lane < m) ? csr_pad[start + c + lane] : -1;
        int t = 0;
        for (; t + 16 <= m; t += 16) {
            int s0 = __shfl(sv, t + es);
            int s1 = __shfl(sv, t + 4 + es);
            int s2 = __shfl(sv, t + 8 + es);
            int s3 = __shfl(sv, t + 12 + es);
            float4 v0 = *(const float4*)(g + (size_t)s0 * 64 + fg * 4);
            float4 v1 = *(const float4*)(g + (size_t)s1 * 64 + fg * 4);
            float4 v2 = *(const float4*)(g + (size_t)s2 * 64 + fg * 4);
            float4 v3 = *(const float4*)(g + (size_t)s3 * 64 + fg * 4);
            a0.x += v0.x; a0.y += v0.y; a0.z += v0.z; a0.w += v0.w;
            a1.x += v1.x; a1.y += v1.y; a1.z += v1.z; a1.w += v1.w;
            a2.x += v2.x; a2.y += v2.y; a2.z += v2.z; a2.w += v2.w;
            a3.x += v3.x; a3.y += v3.y; a3.z += v3.z; a3.w += v3.w;
        }
        for (; t < m; t += 4) {
            int e = t + es;                 // <= 63 always
            int s = __shfl(sv, e);
            if (e < m) {
                float4 v = *(const float4*)(g + (size_t)s * 64 + fg * 4);
                a0.x += v.x; a0.y += v.y; a0.z += v.z; a0.w += v.w;
            }
        }
    }
    float4 a;
    a.x = (a0.x + a1.x) + (a2.x + a3.x);
    a.y = (a0.y + a1.y) + (a2.y + a3.y);
    a.z = (a0.z + a1.z) + (a2.z + a3.z);
    a.w = (a0.w + a1.w) + (a2.w + a3.w);
    a.x += __shfl_xor(a.x, 16); a.y += __shfl_xor(a.y, 16);
    a.z += __shfl_xor(a.z, 16); a.w += __shfl_xor(a.w, 16);
    a.x += __shfl_xor(a.x, 32); a.y += __shfl_xor(a.y, 32);
    a.z += __shfl_xor(a.z, 32); a.w += __shfl_xor(a.w, 32);

    if (es == 0) {
        float4 bv = *(const float4*)(bias + fg * 4);
        float4 o;
        o.x = fmaf(dn, a.x, bv.x);
        o.y = fmaf(dn, a.y, bv.y);
        o.z = fmaf(dn, a.z, bv.z);
        o.w = fmaf(dn, a.w, bv.w);
        if (RELU) {
            o.x = fmaxf(o.x, 0.f); o.y = fmaxf(o.y, 0.f);
            o.z = fmaxf(o.z, 0.f); o.w = fmaxf(o.w, 0.f);
        }
        if (POOL) {
            float* pp = pooled + (size_t)batch[node] * 64 + fg * 4;
            atomicAdd(pp + 0, o.x);
            atomicAdd(pp + 1, o.y);
            atomicAdd(pp + 2, o.z);
            atomicAdd(pp + 3, o.w);
        } else {
            *(float4*)(out + (size_t)node * 64 + fg * 4) = o;
        }
    }
}

// ---------------------------------------------------------------- final FC, wave per graph
__global__ __launch_bounds__(256) void final_fc(const float* __restrict__ pooled,
                                                const int* __restrict__ cntg,
                                                const float* __restrict__ fc_w,
                                                const float* __restrict__ fc_b,
                                                float* __restrict__ out, int g) {
    int gid = (blockIdx.x * 256 + threadIdx.x) >> 6;
    int lane = threadIdx.x & 63;
    if (gid >= g) return;
    float c = fmaxf((float)cntg[gid], 1.0f);
    float v = pooled[(size_t)gid * 64 + lane] / c * fc_w[lane];
#pragma unroll
    for (int off = 32; off > 0; off >>= 1) v += __shfl_down(v, off);
    if (lane == 0) out[gid] = v + fc_b[0];
}

// ---------------------------------------------------------------- launch
extern "C" void kernel_launch(void* const* d_in, const int* in_sizes, int n_in,
                              void* d_out, int out_size, void* d_ws, size_t ws_size,
                              hipStream_t stream) {
    const float* x    = (const float*)d_in[0];
    const int*   eidx = (const int*)d_in[1];     // [2, E] flat: src row then dst row
    const int*   batch= (const int*)d_in[2];
    const float* W1   = (const float*)d_in[4];
    const float* b1   = (const float*)d_in[5];
    const float* W2   = (const float*)d_in[6];
    const float* b2   = (const float*)d_in[7];
    const float* fc_w = (const float*)d_in[8];
    const float* fc_b = (const float*)d_in[9];
    float* out = (float*)d_out;

    const int N = in_sizes[0] / IN_FEAT;
    const int E = in_sizes[1] / 2;
    const int G = N_GRAPHS;
    const int* src = eidx;
    const int* dst = eidx + E;

    // workspace carve (all chunks 16B-aligned)
    char* w = (char*)d_ws;
    float* g1   = (float*)w; w += (size_t)N * 64 * 4;       // dinv * (x @ W1)
    float* h1r  = (float*)w; w += (size_t)N * 64 * 4;       // relu(conv1)
    float* g2   = (float*)w; w += (size_t)N * 64 * 4;       // dinv * (h1r @ W2)
    int*   degi = (int*)w;   w += (size_t)N * 4;
    int*   csrp = (int*)w;   w += (size_t)N * CAP * 4;      // padded CSR (38.4 MB)
    float* pooled = (float*)w; w += (size_t)G * 64 * 4;
    int*   cntg = (int*)w;   w += (size_t)G * 4;
    short* w1hi = (short*)w; w += (size_t)IN_FEAT * 64 * 2;
    short* w1lo = (short*)w; w += (size_t)IN_FEAT * 64 * 2;
    short* w2hi = (short*)w; w += (size_t)HIDDEN * 64 * 2;
    short* w2lo = (short*)w; w += (size_t)HIDDEN * 64 * 2;

    fused_init<<<(G * 64 + 255) / 256, 256, 0, stream>>>(pooled, degi, cntg, batch, N, G);
    split_w<<<(IN_FEAT * 64 + 255) / 256, 256, 0, stream>>>(W1, w1hi, w1lo, IN_FEAT);
    split_w<<<(HIDDEN * 64 + 255) / 256, 256, 0, stream>>>(W2, w2hi, w2lo, HIDDEN);
    deg_scatter<<<(E / 4 + 255) / 256, 256, 0, stream>>>(src, dst, degi, csrp, E);

    gemm_mfma<IN_FEAT><<<(N + 63) / 64, 256, 0, stream>>>(x, w1hi, w1lo, degi, g1, N);
    gcn_gather<true, false><<<(N * 64 + 255) / 256, 256, 0, stream>>>(
        g1, degi, csrp, b1, h1r, nullptr, batch, N);
    gemm_mfma<HIDDEN><<<(N + 63) / 64, 256, 0, stream>>>(h1r, w2hi, w2lo, degi, g2, N);
    gcn_gather<false, true><<<(N * 64 + 255) / 256, 256, 0, stream>>>(
        g2, degi, csrp, b2, nullptr, pooled, batch, N);
    final_fc<<<(G * 64 + 255) / 256, 256, 0, stream>>>(pooled, cntg, fc_w, fc_b, out, G);
}

// Round 4
// 742.958 us; speedup vs baseline: 1.1752x; 1.1752x over previous
//
#include <hip/hip_runtime.h>
#include <hip/hip_bf16.h>

#define N_NODES  100000
#define N_EDGES  3200000
#define IN_FEAT  512
#define HIDDEN   64
#define N_GRAPHS 2048
#define BSH      8         // bucket = dst >> 8  (256 nodes per bucket)
#define NPB      256       // nodes per bucket
#define NBK      512       // bucket array capacity (actual nb = ceil(N/256) = 391)
#define BCAP     10240     // max edges per bucket in LDS (mean 8192, sigma ~90 -> +22 sigma)
#define CH       4096      // edges per block in bucket_scatter

typedef __attribute__((ext_vector_type(8))) short short8;
typedef __attribute__((ext_vector_type(4))) float floatx4;

// RNE fp32 -> bf16 hi + bf16 lo split (hi+lo captures ~16 mantissa bits)
__device__ inline void bf16_split(float f, short& hi, short& lo) {
    unsigned u = __float_as_uint(f);
    unsigned r = (u + 0x7fffu + ((u >> 16) & 1u)) >> 16;     // RNE to bf16
    float fh = __uint_as_float(r << 16);
    float fl = f - fh;                                        // exact
    unsigned v = __float_as_uint(fl);
    unsigned s = (v + 0x7fffu + ((v >> 16) & 1u)) >> 16;
    hi = (short)r;
    lo = (short)s;
}

// ---------------------------------------------------------------- fused init
// pooled = 0; bcnt = 0; cntg via binary search on SORTED batch
__global__ __launch_bounds__(256) void fused_init(float* __restrict__ pooled,
                                                  int* __restrict__ cntg,
                                                  int* __restrict__ bcnt,
                                                  const int* __restrict__ batch,
                                                  int n, int g) {
    int i = blockIdx.x * 256 + threadIdx.x;      // grid covers g*64 = 131072
    if (i < g * 64) pooled[i] = 0.f;
    if (i < NBK) bcnt[i] = 0;
    if (i < g) {
        int lo0 = 0, hi0 = n;
        while (lo0 < hi0) { int m = (lo0 + hi0) >> 1; if (batch[m] < i) lo0 = m + 1; else hi0 = m; }
        int lo1 = lo0, hi1 = n;
        while (lo1 < hi1) { int m = (lo1 + hi1) >> 1; if (batch[m] < i + 1) lo1 = m + 1; else hi1 = m; }
        cntg[i] = lo1 - lo0;
    }
}

// ---------------------------------------------------------------- W pre-split
__global__ __launch_bounds__(256) void split_w(const float* __restrict__ W,
                                               short* __restrict__ hi_t,
                                               short* __restrict__ lo_t, int K) {
    int i = blockIdx.x * 256 + threadIdx.x;       // i = k*64 + c
    if (i < K * 64) {
        int k = i >> 6, c = i & 63;
        short h, l;
        bf16_split(W[i], h, l);
        hi_t[c * K + k] = h;
        lo_t[c * K + k] = l;
    }
}

// ---------------------------------------------------------------- bucket histogram
// LDS-aggregated, then one global atomicAdd per (block, bucket).
__global__ __launch_bounds__(256) void bucket_count(const int* __restrict__ dst,
                                                    int* __restrict__ bcnt, int e) {
    __shared__ int lcnt[NBK];
    for (int b = threadIdx.x; b < NBK; b += 256) lcnt[b] = 0;
    __syncthreads();
    int i = blockIdx.x * 256 + threadIdx.x;
    int stride = gridDim.x * 256;
    for (; i < e; i += stride) atomicAdd(&lcnt[dst[i] >> BSH], 1);
    __syncthreads();
    for (int b = threadIdx.x; b < NBK; b += 256) {
        int c = lcnt[b];
        if (c) atomicAdd(&bcnt[b], c);
    }
}

// ---------------------------------------------------------------- bucket scan (1 block, 512 thr)
// exclusive scan of bucket counts -> boff[0..nb], and init tails = offsets
__global__ void bucket_scan(const int* __restrict__ bcnt,
                            int* __restrict__ boff,
                            int* __restrict__ tail, int nb) {
    __shared__ int sA[512], sB[512];
    int t = threadIdx.x;
    int v = (t < nb) ? bcnt[t] : 0;
    sA[t] = v;
    __syncthreads();
    int* pin = sA; int* pout = sB;
    for (int off = 1; off < 512; off <<= 1) {
        pout[t] = pin[t] + ((t >= off) ? pin[t - off] : 0);
        __syncthreads();
        int* tmp = pin; pin = pout; pout = tmp;
    }
    if (t < nb) { boff[t] = pin[t] - v; tail[t] = pin[t] - v; }
    if (t == 0) boff[nb] = pin[nb - 1];
}

// ---------------------------------------------------------------- bucket scatter
// Edges -> per-bucket files of packed (dstLow8 << 17) | src17. Bucket files grow
// monotonically at ~391 tails -> live write window ~= 391 cache lines -> L2
// coalesces into full 64B lines (round-2 lesson: scatter cost = live window vs L2).
__global__ __launch_bounds__(256) void bucket_scatter(const int* __restrict__ src,
                                                      const int* __restrict__ dst,
                                                      int* __restrict__ tail,
                                                      unsigned* __restrict__ packed, int e) {
    __shared__ int lcnt[NBK];
    __shared__ int sbase[NBK];
    int t = threadIdx.x;
    for (int b = t; b < NBK; b += 256) lcnt[b] = 0;
    __syncthreads();
    int base = blockIdx.x * CH;
    int bk[16]; int rk[16]; unsigned pk[16];
#pragma unroll
    for (int j = 0; j < 16; j++) {
        int idx = base + j * 256 + t;
        bk[j] = -1;
        if (idx < e) {
            int d = dst[idx], s = src[idx];
            bk[j] = d >> BSH;
            pk[j] = ((unsigned)(d & (NPB - 1)) << 17) | (unsigned)s;
            rk[j] = atomicAdd(&lcnt[bk[j]], 1);
        }
    }
    __syncthreads();
    for (int b = t; b < NBK; b += 256) {
        int c = lcnt[b];
        sbase[b] = c ? atomicAdd(&tail[b], c) : 0;
    }
    __syncthreads();
#pragma unroll
    for (int j = 0; j < 16; j++)
        if (bk[j] >= 0) packed[sbase[bk[j]] + rk[j]] = pk[j];
}

// ---------------------------------------------------------------- per-bucket CSR build
// One block per bucket: edges to LDS (40KB), per-node count, LDS scan, scatter into
// the bucket's contiguous CSR region (~32KB L2-resident window -> full-line evictions).
// Emits row_start and degi (edge count + 1 self-loop) -- no global scans.
// Total static LDS = 45KB (< 64KB per-workgroup static limit).
__global__ __launch_bounds__(256) void bucket_csr(const unsigned* __restrict__ packed,
                                                  const int* __restrict__ boff,
                                                  int* __restrict__ csr,
                                                  int* __restrict__ row_start,
                                                  int* __restrict__ degi, int n) {
    __shared__ unsigned ed[BCAP];                               // 40 KB
    __shared__ int deg[NPB], excl[NPB], sA[NPB], sB[NPB];       // 4 KB
    int b = blockIdx.x, t = threadIdx.x;
    int gbase = boff[b];
    int cnt = boff[b + 1] - gbase;
    if (cnt > BCAP) cnt = BCAP;                  // statistically unreachable guard
    for (int i = t; i < cnt; i += 256) ed[i] = packed[gbase + i];
    deg[t] = 0;
    __syncthreads();
    for (int i = t; i < cnt; i += 256) atomicAdd(&deg[ed[i] >> 17], 1);
    __syncthreads();
    // inclusive Hillis-Steele scan over 256 (ping-pong)
    sA[t] = deg[t];
    __syncthreads();
    int* pin = sA; int* pout = sB;
    for (int off = 1; off < NPB; off <<= 1) {
        pout[t] = pin[t] + ((t >= off) ? pin[t - off] : 0);
        __syncthreads();
        int* tmp = pin; pin = pout; pout = tmp;
    }
    excl[t] = pin[t] - deg[t];
    __syncthreads();
    int n0 = b << BSH;
    if (n0 + t < n) {
        row_start[n0 + t] = gbase + excl[t];
        degi[n0 + t] = deg[t] + 1;               // + self-loop
    }
    __syncthreads();
    // reuse deg[] as bump cursors
    deg[t] = excl[t];
    __syncthreads();
    for (int i = t; i < cnt; i += 256) {
        unsigned p = ed[i];
        int d = p >> 17;
        int slot = atomicAdd(&deg[d], 1);
        csr[gbase + slot] = (int)(p & 0x1FFFFu);
    }
}

// ---------------------------------------------------------------- split-bf16 MFMA GEMM
// Y[n,64] = dinv[n] * (X[n,K] @ W[K,64]); W pre-split (transposed [col][K]).
template <int K>
__global__ __launch_bounds__(256) void gemm_mfma(const float* __restrict__ X,
                                                 const short* __restrict__ Whi,
                                                 const short* __restrict__ Wlo,
                                                 const int* __restrict__ degi,
                                                 float* __restrict__ Y, int nrows) {
    constexpr int BSTR = 40;                   // 32 + 8 pad: bank-conflict-free reads
    __shared__ short bhi[64 * BSTR];
    __shared__ short blo[64 * BSTR];

    const int t    = threadIdx.x;
    const int wave = t >> 6;
    const int lane = t & 63;
    const int quad = lane >> 4;
    const int l16  = lane & 15;

    const int arow   = blockIdx.x * 64 + wave * 16 + l16;
    const bool rvalid = arow < nrows;
    const float* xrow = X + (size_t)arow * K;

    const int scol = t & 63;
    const int skg  = t >> 6;
    const short* whp = Whi + (size_t)scol * K + skg * 8;
    const short* wlp = Wlo + (size_t)scol * K + skg * 8;

    floatx4 acc[4] = {};

#pragma unroll 1
    for (int k0 = 0; k0 < K; k0 += 32) {
        short8 whi = *(const short8*)(whp + k0);
        short8 wlo = *(const short8*)(wlp + k0);

        float av[8] = {0.f, 0.f, 0.f, 0.f, 0.f, 0.f, 0.f, 0.f};
        if (rvalid) {
            float4 p0 = *(const float4*)(xrow + k0 + quad * 8);
            float4 p1 = *(const float4*)(xrow + k0 + quad * 8 + 4);
            av[0] = p0.x; av[1] = p0.y; av[2] = p0.z; av[3] = p0.w;
            av[4] = p1.x; av[5] = p1.y; av[6] = p1.z; av[7] = p1.w;
        }
        short8 ahi, alo;
#pragma unroll
        for (int j = 0; j < 8; j++) { short h, l; bf16_split(av[j], h, l); ahi[j] = h; alo[j] = l; }

        __syncthreads();   // prior chunk's B reads complete before overwrite
        *(short8*)&bhi[scol * BSTR + skg * 8] = whi;
        *(short8*)&blo[scol * BSTR + skg * 8] = wlo;
        __syncthreads();   // B staged

#pragma unroll
        for (int ct = 0; ct < 4; ct++) {
            int col = ct * 16 + l16;
            short8 bh = *(short8*)&bhi[col * BSTR + quad * 8];
            short8 bl = *(short8*)&blo[col * BSTR + quad * 8];
            acc[ct] = __builtin_amdgcn_mfma_f32_16x16x32_bf16(ahi, bh, acc[ct], 0, 0, 0);
            acc[ct] = __builtin_amdgcn_mfma_f32_16x16x32_bf16(ahi, bl, acc[ct], 0, 0, 0);
            acc[ct] = __builtin_amdgcn_mfma_f32_16x16x32_bf16(alo, bh, acc[ct], 0, 0, 0);
        }
    }

    // C/D layout: col = ct*16 + l16, row = wave*16 + quad*4 + r
#pragma unroll
    for (int r = 0; r < 4; r++) {
        int orow = blockIdx.x * 64 + wave * 16 + quad * 4 + r;
        if (orow < nrows) {
            float dv = 1.0f / sqrtf((float)degi[orow]);
#pragma unroll
            for (int ct = 0; ct < 4; ct++)
                Y[(size_t)orow * 64 + ct * 16 + l16] = acc[ct][r] * dv;
        }
    }
}

// ---------------------------------------------------------------- GCN gather
// wave per node; lane = fg (0..15, feature group of 4) + 16*es (0..3 edge slot).
// Depth-4 (round-0 form): VGPR 28, occ ~75%. Round-1 showed deeper unroll only
// costs occupancy -- the limit is L2-miss service, not per-wave MLP.
template <bool RELU, bool POOL>
__global__ __launch_bounds__(256) void gcn_gather(const float* __restrict__ g,
                                                  const int* __restrict__ degi,
                                                  const int* __restrict__ row_start,
                                                  const int* __restrict__ csr_src,
                                                  const float* __restrict__ bias,
                                                  float* __restrict__ out,
                                                  float* __restrict__ pooled,
                                                  const int* __restrict__ batch, int n) {
    int node = (blockIdx.x * 256 + threadIdx.x) >> 6;
    int lane = threadIdx.x & 63;
    int es = lane >> 4;
    int fg = lane & 15;
    if (node >= n) return;

    int dg = degi[node];
    int de = dg - 1;                            // edge count in CSR row
    float dn = 1.0f / sqrtf((float)dg);
    int start = row_start[node];

    float4 a0 = make_float4(0.f, 0.f, 0.f, 0.f);
    float4 a1 = a0, a2 = a0, a3 = a0;
    if (es == 0) a0 = *(const float4*)(g + (size_t)node * 64 + fg * 4);  // self-loop

    for (int c = 0; c < de; c += 64) {
        int m = min(64, de - c);
        int sv = (lane < m) ? csr_src[start + c + lane] : -1;
        int t = 0;
        for (; t + 16 <= m; t += 16) {
            int s0 = __shfl(sv, t + es);
            int s1 = __shfl(sv, t + 4 + es);
            int s2 = __shfl(sv, t + 8 + es);
            int s3 = __shfl(sv, t + 12 + es);
            float4 v0 = *(const float4*)(g + (size_t)s0 * 64 + fg * 4);
            float4 v1 = *(const float4*)(g + (size_t)s1 * 64 + fg * 4);
            float4 v2 = *(const float4*)(g + (size_t)s2 * 64 + fg * 4);
            float4 v3 = *(const float4*)(g + (size_t)s3 * 64 + fg * 4);
            a0.x += v0.x; a0.y += v0.y; a0.z += v0.z; a0.w += v0.w;
            a1.x += v1.x; a1.y += v1.y; a1.z += v1.z; a1.w += v1.w;
            a2.x += v2.x; a2.y += v2.y; a2.z += v2.z; a2.w += v2.w;
            a3.x += v3.x; a3.y += v3.y; a3.z += v3.z; a3.w += v3.w;
        }
        for (; t < m; t += 4) {
            int e = t + es;                 // <= 63 always
            int s = __shfl(sv, e);
            if (e < m) {
                float4 v = *(const float4*)(g + (size_t)s * 64 + fg * 4);
                a0.x += v.x; a0.y += v.y; a0.z += v.z; a0.w += v.w;
            }
        }
    }
    float4 a;
    a.x = (a0.x + a1.x) + (a2.x + a3.x);
    a.y = (a0.y + a1.y) + (a2.y + a3.y);
    a.z = (a0.z + a1.z) + (a2.z + a3.z);
    a.w = (a0.w + a1.w) + (a2.w + a3.w);
    a.x += __shfl_xor(a.x, 16); a.y += __shfl_xor(a.y, 16);
    a.z += __shfl_xor(a.z, 16); a.w += __shfl_xor(a.w, 16);
    a.x += __shfl_xor(a.x, 32); a.y += __shfl_xor(a.y, 32);
    a.z += __shfl_xor(a.z, 32); a.w += __shfl_xor(a.w, 32);

    if (es == 0) {
        float4 bv = *(const float4*)(bias + fg * 4);
        float4 o;
        o.x = fmaf(dn, a.x, bv.x);
        o.y = fmaf(dn, a.y, bv.y);
        o.z = fmaf(dn, a.z, bv.z);
        o.w = fmaf(dn, a.w, bv.w);
        if (RELU) {
            o.x = fmaxf(o.x, 0.f); o.y = fmaxf(o.y, 0.f);
            o.z = fmaxf(o.z, 0.f); o.w = fmaxf(o.w, 0.f);
        }
        if (POOL) {
            float* pp = pooled + (size_t)batch[node] * 64 + fg * 4;
            atomicAdd(pp + 0, o.x);
            atomicAdd(pp + 1, o.y);
            atomicAdd(pp + 2, o.z);
            atomicAdd(pp + 3, o.w);
        } else {
            *(float4*)(out + (size_t)node * 64 + fg * 4) = o;
        }
    }
}

// ---------------------------------------------------------------- final FC, wave per graph
__global__ __launch_bounds__(256) void final_fc(const float* __restrict__ pooled,
                                                const int* __restrict__ cntg,
                                                const float* __restrict__ fc_w,
                                                const float* __restrict__ fc_b,
                                                float* __restrict__ out, int g) {
    int gid = (blockIdx.x * 256 + threadIdx.x) >> 6;
    int lane = threadIdx.x & 63;
    if (gid >= g) return;
    float c = fmaxf((float)cntg[gid], 1.0f);
    float v = pooled[(size_t)gid * 64 + lane] / c * fc_w[lane];
#pragma unroll
    for (int off = 32; off > 0; off >>= 1) v += __shfl_down(v, off);
    if (lane == 0) out[gid] = v + fc_b[0];
}

// ---------------------------------------------------------------- launch
extern "C" void kernel_launch(void* const* d_in, const int* in_sizes, int n_in,
                              void* d_out, int out_size, void* d_ws, size_t ws_size,
                              hipStream_t stream) {
    const float* x    = (const float*)d_in[0];
    const int*   eidx = (const int*)d_in[1];     // [2, E] flat: src row then dst row
    const int*   batch= (const int*)d_in[2];
    const float* W1   = (const float*)d_in[4];
    const float* b1   = (const float*)d_in[5];
    const float* W2   = (const float*)d_in[6];
    const float* b2   = (const float*)d_in[7];
    const float* fc_w = (const float*)d_in[8];
    const float* fc_b = (const float*)d_in[9];
    float* out = (float*)d_out;

    const int N = in_sizes[0] / IN_FEAT;
    const int E = in_sizes[1] / 2;
    const int G = N_GRAPHS;
    const int* src = eidx;
    const int* dst = eidx + E;
    const int nb = (N + NPB - 1) >> BSH;         // 391 buckets

    // workspace carve (all chunks 16B-aligned)
    char* w = (char*)d_ws;
    float* g1   = (float*)w; w += (size_t)N * 64 * 4;       // dinv * (x @ W1)
    float* h1r  = (float*)w; w += (size_t)N * 64 * 4;       // relu(conv1)
    float* g2   = (float*)w; w += (size_t)N * 64 * 4;       // dinv * (h1r @ W2)
    int*   degi = (int*)w;   w += (size_t)N * 4;
    int*   rowst= (int*)w;   w += (size_t)N * 4;
    int*   bcnt = (int*)w;   w += NBK * 4;
    int*   boff = (int*)w;   w += (NBK + 1) * 4 + 12;       // keep 16B alignment
    int*   tail = (int*)w;   w += NBK * 4;
    unsigned* packed = (unsigned*)w; w += (size_t)E * 4;    // bucketed packed edges
    int*   csrs = (int*)w;   w += (size_t)E * 4;            // compact CSR srcs
    float* pooled = (float*)w; w += (size_t)G * 64 * 4;
    int*   cntg = (int*)w;   w += (size_t)G * 4;
    short* w1hi = (short*)w; w += (size_t)IN_FEAT * 64 * 2;
    short* w1lo = (short*)w; w += (size_t)IN_FEAT * 64 * 2;
    short* w2hi = (short*)w; w += (size_t)HIDDEN * 64 * 2;
    short* w2lo = (short*)w; w += (size_t)HIDDEN * 64 * 2;

    fused_init<<<(G * 64 + 255) / 256, 256, 0, stream>>>(pooled, cntg, bcnt, batch, N, G);
    split_w<<<(IN_FEAT * 64 + 255) / 256, 256, 0, stream>>>(W1, w1hi, w1lo, IN_FEAT);
    split_w<<<(HIDDEN * 64 + 255) / 256, 256, 0, stream>>>(W2, w2hi, w2lo, HIDDEN);

    bucket_count<<<2048, 256, 0, stream>>>(dst, bcnt, E);
    bucket_scan<<<1, 512, 0, stream>>>(bcnt, boff, tail, nb);
    bucket_scatter<<<(E + CH - 1) / CH, 256, 0, stream>>>(src, dst, tail, packed, E);
    bucket_csr<<<nb, 256, 0, stream>>>(packed, boff, csrs, rowst, degi, N);

    gemm_mfma<IN_FEAT><<<(N + 63) / 64, 256, 0, stream>>>(x, w1hi, w1lo, degi, g1, N);
    gcn_gather<true, false><<<(N * 64 + 255) / 256, 256, 0, stream>>>(
        g1, degi, rowst, csrs, b1, h1r, nullptr, batch, N);
    gemm_mfma<HIDDEN><<<(N + 63) / 64, 256, 0, stream>>>(h1r, w2hi, w2lo, degi, g2, N);
    gcn_gather<false, true><<<(N * 64 + 255) / 256, 256, 0, stream>>>(
        g2, degi, rowst, csrs, b2, nullptr, pooled, batch, N);
    final_fc<<<(G * 64 + 255) / 256, 256, 0, stream>>>(pooled, cntg, fc_w, fc_b, out, G);
}

// Round 5
// 731.762 us; speedup vs baseline: 1.1932x; 1.0153x over previous
//
#include <hip/hip_runtime.h>
#include <hip/hip_bf16.h>

#define N_NODES  100000
#define N_EDGES  3200000
#define IN_FEAT  512
#define HIDDEN   64
#define N_GRAPHS 2048
#define BSH      8         // bucket = dst >> 8  (256 nodes per bucket)
#define NPB      256       // nodes per bucket
#define NBK      512       // bucket array capacity (actual nb = ceil(N/256) = 391)
#define BCAP     10240     // padded edges per bucket (mean 8192, sigma ~90 -> +22 sigma)
#define CH       4096      // edges per block in bucket_scatter

typedef __attribute__((ext_vector_type(8))) short short8;
typedef __attribute__((ext_vector_type(4))) float floatx4;

// RNE fp32 -> bf16 hi + bf16 lo split (hi+lo captures ~16 mantissa bits)
__device__ inline void bf16_split(float f, short& hi, short& lo) {
    unsigned u = __float_as_uint(f);
    unsigned r = (u + 0x7fffu + ((u >> 16) & 1u)) >> 16;     // RNE to bf16
    float fh = __uint_as_float(r << 16);
    float fl = f - fh;                                        // exact
    unsigned v = __float_as_uint(fl);
    unsigned s = (v + 0x7fffu + ((v >> 16) & 1u)) >> 16;
    hi = (short)r;
    lo = (short)s;
}

// ---------------------------------------------------------------- fused init (+ W pre-split)
// pooled = 0; tails = padded bucket bases; cntg via binary search on SORTED batch;
// W1/W2 split+transpose folded in (2 fewer launches).
__global__ __launch_bounds__(256) void fused_init(float* __restrict__ pooled,
                                                  int* __restrict__ cntg,
                                                  int* __restrict__ tail,
                                                  const int* __restrict__ batch,
                                                  const float* __restrict__ W1,
                                                  short* __restrict__ w1hi, short* __restrict__ w1lo,
                                                  const float* __restrict__ W2,
                                                  short* __restrict__ w2hi, short* __restrict__ w2lo,
                                                  int n, int g) {
    int i = blockIdx.x * 256 + threadIdx.x;      // grid = 131072 threads
    if (i < g * 64) pooled[i] = 0.f;
    if (i < NBK) tail[i] = i * BCAP;
    if (i < IN_FEAT * 64) {
        int k = i >> 6, c = i & 63;
        short h, l;
        bf16_split(W1[i], h, l);
        w1hi[c * IN_FEAT + k] = h;
        w1lo[c * IN_FEAT + k] = l;
    }
    if (i < HIDDEN * 64) {
        int k = i >> 6, c = i & 63;
        short h, l;
        bf16_split(W2[i], h, l);
        w2hi[c * HIDDEN + k] = h;
        w2lo[c * HIDDEN + k] = l;
    }
    if (i < g) {
        int lo0 = 0, hi0 = n;
        while (lo0 < hi0) { int m = (lo0 + hi0) >> 1; if (batch[m] < i) lo0 = m + 1; else hi0 = m; }
        int lo1 = lo0, hi1 = n;
        while (lo1 < hi1) { int m = (lo1 + hi1) >> 1; if (batch[m] < i + 1) lo1 = m + 1; else hi1 = m; }
        cntg[i] = lo1 - lo0;
    }
}

// ---------------------------------------------------------------- bucket scatter (single pass)
// Edges -> padded per-bucket files of packed (dstLow8 << 17) | src17. Tails start at
// b*BCAP; files grow monotonically at ~391 tails -> live write window ~= 391 cache
// lines -> L2 coalesces full 64B lines (round-2 lesson: cost = live window vs L2).
// No count/scan prepass needed.
__global__ __launch_bounds__(256) void bucket_scatter(const int* __restrict__ src,
                                                      const int* __restrict__ dst,
                                                      int* __restrict__ tail,
                                                      unsigned* __restrict__ packed, int e) {
    __shared__ int lcnt[NBK];
    __shared__ int sbase[NBK];
    int t = threadIdx.x;
    for (int b = t; b < NBK; b += 256) lcnt[b] = 0;
    __syncthreads();
    int base = blockIdx.x * CH;
    int bk[16]; int rk[16]; unsigned pk[16];
#pragma unroll
    for (int j = 0; j < 16; j++) {
        int idx = base + j * 256 + t;
        bk[j] = -1;
        if (idx < e) {
            int d = dst[idx], s = src[idx];
            bk[j] = d >> BSH;
            pk[j] = ((unsigned)(d & (NPB - 1)) << 17) | (unsigned)s;
            rk[j] = atomicAdd(&lcnt[bk[j]], 1);
        }
    }
    __syncthreads();
    for (int b = t; b < NBK; b += 256) {
        int c = lcnt[b];
        sbase[b] = c ? atomicAdd(&tail[b], c) : 0;
    }
    __syncthreads();
#pragma unroll
    for (int j = 0; j < 16; j++)
        if (bk[j] >= 0) {
            int slot = sbase[bk[j]] + rk[j];
            if (slot < (bk[j] + 1) * BCAP)       // overflow guard (statistically unreachable)
                packed[slot] = pk[j];
        }
}

// ---------------------------------------------------------------- bucket scan (1 block, 512 thr)
// counts from final tails -> exclusive scan -> compact CSR offsets boff[0..nb]
__global__ void bucket_scan(const int* __restrict__ tail,
                            int* __restrict__ boff, int nb) {
    __shared__ int sA[512], sB[512];
    int t = threadIdx.x;
    int v = (t < nb) ? min(tail[t] - t * BCAP, BCAP) : 0;
    sA[t] = v;
    __syncthreads();
    int* pin = sA; int* pout = sB;
    for (int off = 1; off < 512; off <<= 1) {
        pout[t] = pin[t] + ((t >= off) ? pin[t - off] : 0);
        __syncthreads();
        int* tmp = pin; pin = pout; pout = tmp;
    }
    if (t < nb) boff[t] = pin[t] - v;
    if (t == 0) boff[nb] = pin[nb - 1];
}

// ---------------------------------------------------------------- per-bucket CSR build
// One block per bucket: padded-file edges to LDS (40KB), per-node count, LDS scan,
// scatter into the bucket's contiguous CSR region (~32KB L2-resident window).
// Emits row_start and degi (edge count + 1 self-loop). Static LDS = 44KB < 64KB.
__global__ __launch_bounds__(256) void bucket_csr(const unsigned* __restrict__ packed,
                                                  const int* __restrict__ boff,
                                                  int* __restrict__ csr,
                                                  int* __restrict__ row_start,
                                                  int* __restrict__ degi, int n) {
    __shared__ unsigned ed[BCAP];                               // 40 KB
    __shared__ int deg[NPB], excl[NPB], sA[NPB], sB[NPB];       // 4 KB
    int b = blockIdx.x, t = threadIdx.x;
    int gbase = boff[b];
    int cnt = boff[b + 1] - gbase;
    if (cnt > BCAP) cnt = BCAP;
    const unsigned* pbase = packed + (size_t)b * BCAP;
    for (int i = t; i < cnt; i += 256) ed[i] = pbase[i];
    deg[t] = 0;
    __syncthreads();
    for (int i = t; i < cnt; i += 256) atomicAdd(&deg[ed[i] >> 17], 1);
    __syncthreads();
    // inclusive Hillis-Steele scan over 256 (ping-pong)
    sA[t] = deg[t];
    __syncthreads();
    int* pin = sA; int* pout = sB;
    for (int off = 1; off < NPB; off <<= 1) {
        pout[t] = pin[t] + ((t >= off) ? pin[t - off] : 0);
        __syncthreads();
        int* tmp = pin; pin = pout; pout = tmp;
    }
    excl[t] = pin[t] - deg[t];
    __syncthreads();
    int n0 = b << BSH;
    if (n0 + t < n) {
        row_start[n0 + t] = gbase + excl[t];
        degi[n0 + t] = deg[t] + 1;               // + self-loop
    }
    __syncthreads();
    deg[t] = excl[t];                            // reuse as bump cursors
    __syncthreads();
    for (int i = t; i < cnt; i += 256) {
        unsigned p = ed[i];
        int d = p >> 17;
        int slot = atomicAdd(&deg[d], 1);
        csr[gbase + slot] = (int)(p & 0x1FFFFu);
    }
}

// ---------------------------------------------------------------- split-bf16 MFMA GEMM, barrier-free
// Y[n,64] = dinv[n] * (X[n,K] @ W[K,64]). W pre-split transposed [col][K], so each
// lane's B fragment = contiguous short8 at Wt[col*K + k0 + quad*8] -- direct from
// L1/L2 (128KB table). No LDS, no __syncthreads: the 16 per-chunk barrier drains
// that serialized HBM X-loads are gone; waves stream freely. Bit-identical MFMA
// inputs -> bit-identical output vs the LDS-staged version.
template <int K>
__global__ __launch_bounds__(256) void gemm_mfma(const float* __restrict__ X,
                                                 const short* __restrict__ Whi,
                                                 const short* __restrict__ Wlo,
                                                 const int* __restrict__ degi,
                                                 float* __restrict__ Y, int nrows) {
    const int t    = threadIdx.x;
    const int wave = t >> 6;
    const int lane = t & 63;
    const int quad = lane >> 4;
    const int l16  = lane & 15;

    const int arow   = blockIdx.x * 64 + wave * 16 + l16;
    const bool rvalid = arow < nrows;
    const float* xrow = X + (size_t)arow * K;

    floatx4 acc[4] = {};

#pragma unroll 1
    for (int k0 = 0; k0 < K; k0 += 32) {
        float av[8] = {0.f, 0.f, 0.f, 0.f, 0.f, 0.f, 0.f, 0.f};
        if (rvalid) {
            float4 p0 = *(const float4*)(xrow + k0 + quad * 8);
            float4 p1 = *(const float4*)(xrow + k0 + quad * 8 + 4);
            av[0] = p0.x; av[1] = p0.y; av[2] = p0.z; av[3] = p0.w;
            av[4] = p1.x; av[5] = p1.y; av[6] = p1.z; av[7] = p1.w;
        }
        short8 ahi, alo;
#pragma unroll
        for (int j = 0; j < 8; j++) { short h, l; bf16_split(av[j], h, l); ahi[j] = h; alo[j] = l; }

#pragma unroll
        for (int ct = 0; ct < 4; ct++) {
            int col = ct * 16 + l16;
            short8 bh = *(const short8*)(Whi + (size_t)col * K + k0 + quad * 8);
            short8 bl = *(const short8*)(Wlo + (size_t)col * K + k0 + quad * 8);
            acc[ct] = __builtin_amdgcn_mfma_f32_16x16x32_bf16(ahi, bh, acc[ct], 0, 0, 0);
            acc[ct] = __builtin_amdgcn_mfma_f32_16x16x32_bf16(ahi, bl, acc[ct], 0, 0, 0);
            acc[ct] = __builtin_amdgcn_mfma_f32_16x16x32_bf16(alo, bh, acc[ct], 0, 0, 0);
        }
    }

    // C/D layout: col = ct*16 + l16, row = wave*16 + quad*4 + r
#pragma unroll
    for (int r = 0; r < 4; r++) {
        int orow = blockIdx.x * 64 + wave * 16 + quad * 4 + r;
        if (orow < nrows) {
            float dv = 1.0f / sqrtf((float)degi[orow]);
#pragma unroll
            for (int ct = 0; ct < 4; ct++)
                Y[(size_t)orow * 64 + ct * 16 + l16] = acc[ct][r] * dv;
        }
    }
}

// ---------------------------------------------------------------- GCN gather
// wave per node; lane = fg (0..15, feature group of 4) + 16*es (0..3 edge slot).
// Depth-4 (round-0 form): VGPR 28, occ ~75%. Round-1 showed deeper unroll only
// costs occupancy -- the limit is L2-miss/fabric line service, not per-wave MLP.
template <bool RELU, bool POOL>
__global__ __launch_bounds__(256) void gcn_gather(const float* __restrict__ g,
                                                  const int* __restrict__ degi,
                                                  const int* __restrict__ row_start,
                                                  const int* __restrict__ csr_src,
                                                  const float* __restrict__ bias,
                                                  float* __restrict__ out,
                                                  float* __restrict__ pooled,
                                                  const int* __restrict__ batch, int n) {
    int node = (blockIdx.x * 256 + threadIdx.x) >> 6;
    int lane = threadIdx.x & 63;
    int es = lane >> 4;
    int fg = lane & 15;
    if (node >= n) return;

    int dg = degi[node];
    int de = dg - 1;                            // edge count in CSR row
    float dn = 1.0f / sqrtf((float)dg);
    int start = row_start[node];

    float4 a0 = make_float4(0.f, 0.f, 0.f, 0.f);
    float4 a1 = a0, a2 = a0, a3 = a0;
    if (es == 0) a0 = *(const float4*)(g + (size_t)node * 64 + fg * 4);  // self-loop

    for (int c = 0; c < de; c += 64) {
        int m = min(64, de - c);
        int sv = (lane < m) ? csr_src[start + c + lane] : -1;
        int t = 0;
        for (; t + 16 <= m; t += 16) {
            int s0 = __shfl(sv, t + es);
            int s1 = __shfl(sv, t + 4 + es);
            int s2 = __shfl(sv, t + 8 + es);
            int s3 = __shfl(sv, t + 12 + es);
            float4 v0 = *(const float4*)(g + (size_t)s0 * 64 + fg * 4);
            float4 v1 = *(const float4*)(g + (size_t)s1 * 64 + fg * 4);
            float4 v2 = *(const float4*)(g + (size_t)s2 * 64 + fg * 4);
            float4 v3 = *(const float4*)(g + (size_t)s3 * 64 + fg * 4);
            a0.x += v0.x; a0.y += v0.y; a0.z += v0.z; a0.w += v0.w;
            a1.x += v1.x; a1.y += v1.y; a1.z += v1.z; a1.w += v1.w;
            a2.x += v2.x; a2.y += v2.y; a2.z += v2.z; a2.w += v2.w;
            a3.x += v3.x; a3.y += v3.y; a3.z += v3.z; a3.w += v3.w;
        }
        for (; t < m; t += 4) {
            int e = t + es;                 // <= 63 always
            int s = __shfl(sv, e);
            if (e < m) {
                float4 v = *(const float4*)(g + (size_t)s * 64 + fg * 4);
                a0.x += v.x; a0.y += v.y; a0.z += v.z; a0.w += v.w;
            }
        }
    }
    float4 a;
    a.x = (a0.x + a1.x) + (a2.x + a3.x);
    a.y = (a0.y + a1.y) + (a2.y + a3.y);
    a.z = (a0.z + a1.z) + (a2.z + a3.z);
    a.w = (a0.w + a1.w) + (a2.w + a3.w);
    a.x += __shfl_xor(a.x, 16); a.y += __shfl_xor(a.y, 16);
    a.z += __shfl_xor(a.z, 16); a.w += __shfl_xor(a.w, 16);
    a.x += __shfl_xor(a.x, 32); a.y += __shfl_xor(a.y, 32);
    a.z += __shfl_xor(a.z, 32); a.w += __shfl_xor(a.w, 32);

    if (es == 0) {
        float4 bv = *(const float4*)(bias + fg * 4);
        float4 o;
        o.x = fmaf(dn, a.x, bv.x);
        o.y = fmaf(dn, a.y, bv.y);
        o.z = fmaf(dn, a.z, bv.z);
        o.w = fmaf(dn, a.w, bv.w);
        if (RELU) {
            o.x = fmaxf(o.x, 0.f); o.y = fmaxf(o.y, 0.f);
            o.z = fmaxf(o.z, 0.f); o.w = fmaxf(o.w, 0.f);
        }
        if (POOL) {
            float* pp = pooled + (size_t)batch[node] * 64 + fg * 4;
            atomicAdd(pp + 0, o.x);
            atomicAdd(pp + 1, o.y);
            atomicAdd(pp + 2, o.z);
            atomicAdd(pp + 3, o.w);
        } else {
            *(float4*)(out + (size_t)node * 64 + fg * 4) = o;
        }
    }
}

// ---------------------------------------------------------------- final FC, wave per graph
__global__ __launch_bounds__(256) void final_fc(const float* __restrict__ pooled,
                                                const int* __restrict__ cntg,
                                                const float* __restrict__ fc_w,
                                                const float* __restrict__ fc_b,
                                                float* __restrict__ out, int g) {
    int gid = (blockIdx.x * 256 + threadIdx.x) >> 6;
    int lane = threadIdx.x & 63;
    if (gid >= g) return;
    float c = fmaxf((float)cntg[gid], 1.0f);
    float v = pooled[(size_t)gid * 64 + lane] / c * fc_w[lane];
#pragma unroll
    for (int off = 32; off > 0; off >>= 1) v += __shfl_down(v, off);
    if (lane == 0) out[gid] = v + fc_b[0];
}

// ---------------------------------------------------------------- launch
extern "C" void kernel_launch(void* const* d_in, const int* in_sizes, int n_in,
                              void* d_out, int out_size, void* d_ws, size_t ws_size,
                              hipStream_t stream) {
    const float* x    = (const float*)d_in[0];
    const int*   eidx = (const int*)d_in[1];     // [2, E] flat: src row then dst row
    const int*   batch= (const int*)d_in[2];
    const float* W1   = (const float*)d_in[4];
    const float* b1   = (const float*)d_in[5];
    const float* W2   = (const float*)d_in[6];
    const float* b2   = (const float*)d_in[7];
    const float* fc_w = (const float*)d_in[8];
    const float* fc_b = (const float*)d_in[9];
    float* out = (float*)d_out;

    const int N = in_sizes[0] / IN_FEAT;
    const int E = in_sizes[1] / 2;
    const int G = N_GRAPHS;
    const int* src = eidx;
    const int* dst = eidx + E;
    const int nb = (N + NPB - 1) >> BSH;         // 391 buckets

    // workspace carve (all chunks 16B-aligned)
    char* w = (char*)d_ws;
    float* g1   = (float*)w; w += (size_t)N * 64 * 4;       // dinv * (x @ W1)
    float* h1r  = (float*)w; w += (size_t)N * 64 * 4;       // relu(conv1)
    float* g2   = (float*)w; w += (size_t)N * 64 * 4;       // dinv * (h1r @ W2)
    int*   degi = (int*)w;   w += (size_t)N * 4;
    int*   rowst= (int*)w;   w += (size_t)N * 4;
    int*   boff = (int*)w;   w += (NBK + 1) * 4 + 12;       // keep 16B alignment
    int*   tail = (int*)w;   w += NBK * 4;
    unsigned* packed = (unsigned*)w; w += (size_t)NBK * BCAP * 4;  // padded bucket files (20MB)
    int*   csrs = (int*)w;   w += (size_t)E * 4;            // compact CSR srcs
    float* pooled = (float*)w; w += (size_t)G * 64 * 4;
    int*   cntg = (int*)w;   w += (size_t)G * 4;
    short* w1hi = (short*)w; w += (size_t)IN_FEAT * 64 * 2;
    short* w1lo = (short*)w; w += (size_t)IN_FEAT * 64 * 2;
    short* w2hi = (short*)w; w += (size_t)HIDDEN * 64 * 2;
    short* w2lo = (short*)w; w += (size_t)HIDDEN * 64 * 2;

    fused_init<<<512, 256, 0, stream>>>(pooled, cntg, tail, batch,
                                        W1, w1hi, w1lo, W2, w2hi, w2lo, N, G);
    bucket_scatter<<<(E + CH - 1) / CH, 256, 0, stream>>>(src, dst, tail, packed, E);
    bucket_scan<<<1, 512, 0, stream>>>(tail, boff, nb);
    bucket_csr<<<nb, 256, 0, stream>>>(packed, boff, csrs, rowst, degi, N);

    gemm_mfma<IN_FEAT><<<(N + 63) / 64, 256, 0, stream>>>(x, w1hi, w1lo, degi, g1, N);
    gcn_gather<true, false><<<(N * 64 + 255) / 256, 256, 0, stream>>>(
        g1, degi, rowst, csrs, b1, h1r, nullptr, batch, N);
    gemm_mfma<HIDDEN><<<(N + 63) / 64, 256, 0, stream>>>(h1r, w2hi, w2lo, degi, g2, N);
    gcn_gather<false, true><<<(N * 64 + 255) / 256, 256, 0, stream>>>(
        g2, degi, rowst, csrs, b2, nullptr, pooled, batch, N);
    final_fc<<<(G * 64 + 255) / 256, 256, 0, stream>>>(pooled, cntg, fc_w, fc_b, out, G);
}

// Round 6
// 702.587 us; speedup vs baseline: 1.2427x; 1.0415x over previous
//
#include <hip/hip_runtime.h>
#include <hip/hip_bf16.h>

#define N_NODES  100000
#define N_EDGES  3200000
#define IN_FEAT  512
#define HIDDEN   64
#define N_GRAPHS 2048
#define BSH      8         // bucket = dst >> 8  (256 nodes per bucket)
#define NPB      256       // nodes per bucket
#define NBK      512       // bucket array capacity (actual nb = ceil(N/256) = 391)
#define BCAP     10240     // padded edges per bucket (mean 8192, sigma ~90 -> +22 sigma)
#define CH       4096      // edges per block in bucket_scatter

typedef __attribute__((ext_vector_type(8))) short short8;
typedef __attribute__((ext_vector_type(4))) float floatx4;

// RNE fp32 -> bf16 hi + bf16 lo split (hi+lo captures ~16 mantissa bits)
__device__ inline void bf16_split(float f, short& hi, short& lo) {
    unsigned u = __float_as_uint(f);
    unsigned r = (u + 0x7fffu + ((u >> 16) & 1u)) >> 16;     // RNE to bf16
    float fh = __uint_as_float(r << 16);
    float fl = f - fh;                                        // exact
    unsigned v = __float_as_uint(fl);
    unsigned s = (v + 0x7fffu + ((v >> 16) & 1u)) >> 16;
    hi = (short)r;
    lo = (short)s;
}

__device__ inline unsigned short bf16_rne(float f) {
    unsigned u = __float_as_uint(f);
    return (unsigned short)((u + 0x7fffu + ((u >> 16) & 1u)) >> 16);
}

__device__ inline float bf16_f32(unsigned short v) {
    return __uint_as_float(((unsigned)v) << 16);
}

// ---------------------------------------------------------------- fused init (+ W1 pre-split)
// pooled = 0; tails = padded bucket bases; cntg via binary search on SORTED batch.
__global__ __launch_bounds__(256) void fused_init(float* __restrict__ pooled,
                                                  int* __restrict__ cntg,
                                                  int* __restrict__ tail,
                                                  const int* __restrict__ batch,
                                                  const float* __restrict__ W1,
                                                  short* __restrict__ w1hi, short* __restrict__ w1lo,
                                                  int n, int g) {
    int i = blockIdx.x * 256 + threadIdx.x;      // grid = 131072 threads
    if (i < g * 64) pooled[i] = 0.f;
    if (i < NBK) tail[i] = i * BCAP;
    if (i < IN_FEAT * 64) {
        int k = i >> 6, c = i & 63;
        short h, l;
        bf16_split(W1[i], h, l);
        w1hi[c * IN_FEAT + k] = h;
        w1lo[c * IN_FEAT + k] = l;
    }
    if (i < g) {
        int lo0 = 0, hi0 = n;
        while (lo0 < hi0) { int m = (lo0 + hi0) >> 1; if (batch[m] < i) lo0 = m + 1; else hi0 = m; }
        int lo1 = lo0, hi1 = n;
        while (lo1 < hi1) { int m = (lo1 + hi1) >> 1; if (batch[m] < i + 1) lo1 = m + 1; else hi1 = m; }
        cntg[i] = lo1 - lo0;
    }
}

// ---------------------------------------------------------------- bucket scatter (single pass)
// Edges -> padded per-bucket files of packed (dstLow8 << 17) | src17. Tails start at
// b*BCAP; files grow monotonically at ~391 tails -> live write window stays
// L2-coalescible (round-2 lesson: scatter cost = live write window vs L2).
__global__ __launch_bounds__(256) void bucket_scatter(const int* __restrict__ src,
                                                      const int* __restrict__ dst,
                                                      int* __restrict__ tail,
                                                      unsigned* __restrict__ packed, int e) {
    __shared__ int lcnt[NBK];
    __shared__ int sbase[NBK];
    int t = threadIdx.x;
    for (int b = t; b < NBK; b += 256) lcnt[b] = 0;
    __syncthreads();
    int base = blockIdx.x * CH;
    int bk[16]; int rk[16]; unsigned pk[16];
#pragma unroll
    for (int j = 0; j < 16; j++) {
        int idx = base + j * 256 + t;
        bk[j] = -1;
        if (idx < e) {
            int d = dst[idx], s = src[idx];
            bk[j] = d >> BSH;
            pk[j] = ((unsigned)(d & (NPB - 1)) << 17) | (unsigned)s;
            rk[j] = atomicAdd(&lcnt[bk[j]], 1);
        }
    }
    __syncthreads();
    for (int b = t; b < NBK; b += 256) {
        int c = lcnt[b];
        sbase[b] = c ? atomicAdd(&tail[b], c) : 0;
    }
    __syncthreads();
#pragma unroll
    for (int j = 0; j < 16; j++)
        if (bk[j] >= 0) {
            int slot = sbase[bk[j]] + rk[j];
            if (slot < (bk[j] + 1) * BCAP)       // overflow guard (statistically unreachable)
                packed[slot] = pk[j];
        }
}

// ---------------------------------------------------------------- bucket scan (1 block, 512 thr)
__global__ void bucket_scan(const int* __restrict__ tail,
                            int* __restrict__ boff, int nb) {
    __shared__ int sA[512], sB[512];
    int t = threadIdx.x;
    int v = (t < nb) ? min(tail[t] - t * BCAP, BCAP) : 0;
    sA[t] = v;
    __syncthreads();
    int* pin = sA; int* pout = sB;
    for (int off = 1; off < 512; off <<= 1) {
        pout[t] = pin[t] + ((t >= off) ? pin[t - off] : 0);
        __syncthreads();
        int* tmp = pin; pin = pout; pout = tmp;
    }
    if (t < nb) boff[t] = pin[t] - v;
    if (t == 0) boff[nb] = pin[nb - 1];
}

// ---------------------------------------------------------------- per-bucket CSR build
// One block per bucket: padded-file edges to LDS (40KB), per-node count, LDS scan,
// scatter into the bucket's contiguous CSR region (~32KB L2-resident window).
// Emits row_start and degi (edge count + 1 self-loop). Static LDS = 44KB < 64KB.
__global__ __launch_bounds__(256) void bucket_csr(const unsigned* __restrict__ packed,
                                                  const int* __restrict__ boff,
                                                  int* __restrict__ csr,
                                                  int* __restrict__ row_start,
                                                  int* __restrict__ degi, int n) {
    __shared__ unsigned ed[BCAP];                               // 40 KB
    __shared__ int deg[NPB], excl[NPB], sA[NPB], sB[NPB];       // 4 KB
    int b = blockIdx.x, t = threadIdx.x;
    int gbase = boff[b];
    int cnt = boff[b + 1] - gbase;
    if (cnt > BCAP) cnt = BCAP;
    const unsigned* pbase = packed + (size_t)b * BCAP;
    for (int i = t; i < cnt; i += 256) ed[i] = pbase[i];
    deg[t] = 0;
    __syncthreads();
    for (int i = t; i < cnt; i += 256) atomicAdd(&deg[ed[i] >> 17], 1);
    __syncthreads();
    sA[t] = deg[t];
    __syncthreads();
    int* pin = sA; int* pout = sB;
    for (int off = 1; off < NPB; off <<= 1) {
        pout[t] = pin[t] + ((t >= off) ? pin[t - off] : 0);
        __syncthreads();
        int* tmp = pin; pin = pout; pout = tmp;
    }
    excl[t] = pin[t] - deg[t];
    __syncthreads();
    int n0 = b << BSH;
    if (n0 + t < n) {
        row_start[n0 + t] = gbase + excl[t];
        degi[n0 + t] = deg[t] + 1;               // + self-loop
    }
    __syncthreads();
    deg[t] = excl[t];                            // reuse as bump cursors
    __syncthreads();
    for (int i = t; i < cnt; i += 256) {
        unsigned p = ed[i];
        int d = p >> 17;
        int slot = atomicAdd(&deg[d], 1);
        csr[gbase + slot] = (int)(p & 0x1FFFFu);
    }
}

// ---------------------------------------------------------------- split-bf16 MFMA GEMM, barrier-free
// Yb[n,64] (bf16) = RNE( dinv[n] * (X[n,K] @ W[K,64]) ). W pre-split transposed
// [col][K]; B fragments stream from L1/L2, no LDS, no barriers.
// bf16 output: halves gather1's table to 12.8MB (footprint AND bytes/edge).
template <int K>
__global__ __launch_bounds__(256) void gemm_mfma(const float* __restrict__ X,
                                                 const short* __restrict__ Whi,
                                                 const short* __restrict__ Wlo,
                                                 const int* __restrict__ degi,
                                                 unsigned short* __restrict__ Yb, int nrows) {
    const int t    = threadIdx.x;
    const int wave = t >> 6;
    const int lane = t & 63;
    const int quad = lane >> 4;
    const int l16  = lane & 15;

    const int arow   = blockIdx.x * 64 + wave * 16 + l16;
    const bool rvalid = arow < nrows;
    const float* xrow = X + (size_t)arow * K;

    floatx4 acc[4] = {};

#pragma unroll 1
    for (int k0 = 0; k0 < K; k0 += 32) {
        float av[8] = {0.f, 0.f, 0.f, 0.f, 0.f, 0.f, 0.f, 0.f};
        if (rvalid) {
            float4 p0 = *(const float4*)(xrow + k0 + quad * 8);
            float4 p1 = *(const float4*)(xrow + k0 + quad * 8 + 4);
            av[0] = p0.x; av[1] = p0.y; av[2] = p0.z; av[3] = p0.w;
            av[4] = p1.x; av[5] = p1.y; av[6] = p1.z; av[7] = p1.w;
        }
        short8 ahi, alo;
#pragma unroll
        for (int j = 0; j < 8; j++) { short h, l; bf16_split(av[j], h, l); ahi[j] = h; alo[j] = l; }

#pragma unroll
        for (int ct = 0; ct < 4; ct++) {
            int col = ct * 16 + l16;
            short8 bh = *(const short8*)(Whi + (size_t)col * K + k0 + quad * 8);
            short8 bl = *(const short8*)(Wlo + (size_t)col * K + k0 + quad * 8);
            acc[ct] = __builtin_amdgcn_mfma_f32_16x16x32_bf16(ahi, bh, acc[ct], 0, 0, 0);
            acc[ct] = __builtin_amdgcn_mfma_f32_16x16x32_bf16(ahi, bl, acc[ct], 0, 0, 0);
            acc[ct] = __builtin_amdgcn_mfma_f32_16x16x32_bf16(alo, bh, acc[ct], 0, 0, 0);
        }
    }

    // C/D layout: col = ct*16 + l16, row = wave*16 + quad*4 + r
#pragma unroll
    for (int r = 0; r < 4; r++) {
        int orow = blockIdx.x * 64 + wave * 16 + quad * 4 + r;
        if (orow < nrows) {
            float dv = 1.0f / sqrtf((float)degi[orow]);
#pragma unroll
            for (int ct = 0; ct < 4; ct++)
                Yb[(size_t)orow * 64 + ct * 16 + l16] = bf16_rne(acc[ct][r] * dv);
        }
    }
}

// ---------------------------------------------------------------- gather1 + fused conv2-GEMM
// wave per node; lane = fg (0..15, feature group of 4) + 16*es (0..3 edge slot).
// Reads bf16 g1 rows (128B/row: half the bytes/edge and half the L2 footprint of
// fp32 -- the gather is miss-service-bound, so both cuts pay directly).
// Epilogue: all lanes hold the reduced h1 row -> o = relu(dn*a + b1); then fuse
// gemm2 in fp32: g2[node][lane] = dn * sum_j o_j * W2[j][lane]  (64 shfl + 64
// L1-hot loads + 64 fma per node). Replaces the gemm_mfma<64> dispatch and the
// 51MB h1r round-trip; fp32 dot is MORE accurate than the split-bf16 MFMA it
// replaces.
__global__ __launch_bounds__(256) void gcn_gather_fuse(const unsigned short* __restrict__ g1b,
                                                       const int* __restrict__ degi,
                                                       const int* __restrict__ row_start,
                                                       const int* __restrict__ csr_src,
                                                       const float* __restrict__ b1,
                                                       const float* __restrict__ W2,
                                                       float* __restrict__ g2, int n) {
    int node = (blockIdx.x * 256 + threadIdx.x) >> 6;
    int lane = threadIdx.x & 63;
    int es = lane >> 4;
    int fg = lane & 15;
    if (node >= n) return;

    int dg = degi[node];
    int de = dg - 1;
    float dn = 1.0f / sqrtf((float)dg);
    int start = row_start[node];

    float4 a0 = make_float4(0.f, 0.f, 0.f, 0.f);
    float4 a1 = a0, a2 = a0, a3 = a0;
    if (es == 0) {                                           // self-loop (bf16 row)
        ushort4 v = *(const ushort4*)(g1b + (size_t)node * 64 + fg * 4);
        a0.x = bf16_f32(v.x); a0.y = bf16_f32(v.y);
        a0.z = bf16_f32(v.z); a0.w = bf16_f32(v.w);
    }

    for (int c = 0; c < de; c += 64) {
        int m = min(64, de - c);
        int sv = (lane < m) ? csr_src[start + c + lane] : -1;
        int t = 0;
        for (; t + 16 <= m; t += 16) {
            int s0 = __shfl(sv, t + es);
            int s1 = __shfl(sv, t + 4 + es);
            int s2 = __shfl(sv, t + 8 + es);
            int s3 = __shfl(sv, t + 12 + es);
            ushort4 v0 = *(const ushort4*)(g1b + (size_t)s0 * 64 + fg * 4);
            ushort4 v1 = *(const ushort4*)(g1b + (size_t)s1 * 64 + fg * 4);
            ushort4 v2 = *(const ushort4*)(g1b + (size_t)s2 * 64 + fg * 4);
            ushort4 v3 = *(const ushort4*)(g1b + (size_t)s3 * 64 + fg * 4);
            a0.x += bf16_f32(v0.x); a0.y += bf16_f32(v0.y); a0.z += bf16_f32(v0.z); a0.w += bf16_f32(v0.w);
            a1.x += bf16_f32(v1.x); a1.y += bf16_f32(v1.y); a1.z += bf16_f32(v1.z); a1.w += bf16_f32(v1.w);
            a2.x += bf16_f32(v2.x); a2.y += bf16_f32(v2.y); a2.z += bf16_f32(v2.z); a2.w += bf16_f32(v2.w);
            a3.x += bf16_f32(v3.x); a3.y += bf16_f32(v3.y); a3.z += bf16_f32(v3.z); a3.w += bf16_f32(v3.w);
        }
        for (; t < m; t += 4) {
            int e = t + es;
            int s = __shfl(sv, e);
            if (e < m) {
                ushort4 v = *(const ushort4*)(g1b + (size_t)s * 64 + fg * 4);
                a0.x += bf16_f32(v.x); a0.y += bf16_f32(v.y);
                a0.z += bf16_f32(v.z); a0.w += bf16_f32(v.w);
            }
        }
    }
    float4 a;
    a.x = (a0.x + a1.x) + (a2.x + a3.x);
    a.y = (a0.y + a1.y) + (a2.y + a3.y);
    a.z = (a0.z + a1.z) + (a2.z + a3.z);
    a.w = (a0.w + a1.w) + (a2.w + a3.w);
    a.x += __shfl_xor(a.x, 16); a.y += __shfl_xor(a.y, 16);
    a.z += __shfl_xor(a.z, 16); a.w += __shfl_xor(a.w, 16);
    a.x += __shfl_xor(a.x, 32); a.y += __shfl_xor(a.y, 32);
    a.z += __shfl_xor(a.z, 32); a.w += __shfl_xor(a.w, 32);

    // all lanes now hold the full reduced row for their fg
    float4 bv = *(const float4*)(b1 + fg * 4);
    float4 o;
    o.x = fmaxf(fmaf(dn, a.x, bv.x), 0.f);
    o.y = fmaxf(fmaf(dn, a.y, bv.y), 0.f);
    o.z = fmaxf(fmaf(dn, a.z, bv.z), 0.f);
    o.w = fmaxf(fmaf(dn, a.w, bv.w), 0.f);

    // fused conv2 matmul: lane computes output column `lane`
    float acc2 = 0.f;
#pragma unroll
    for (int fgj = 0; fgj < 16; fgj++) {
        float4 ov;
        ov.x = __shfl(o.x, fgj);
        ov.y = __shfl(o.y, fgj);
        ov.z = __shfl(o.z, fgj);
        ov.w = __shfl(o.w, fgj);
        const float* wr = W2 + (size_t)(fgj * 4) * 64 + lane;
        acc2 = fmaf(ov.x, wr[0],   acc2);
        acc2 = fmaf(ov.y, wr[64],  acc2);
        acc2 = fmaf(ov.z, wr[128], acc2);
        acc2 = fmaf(ov.w, wr[192], acc2);
    }
    g2[(size_t)node * 64 + lane] = dn * acc2;
}

// ---------------------------------------------------------------- gather2 + mean-pool (fp32, control)
__global__ __launch_bounds__(256) void gcn_gather_pool(const float* __restrict__ g,
                                                       const int* __restrict__ degi,
                                                       const int* __restrict__ row_start,
                                                       const int* __restrict__ csr_src,
                                                       const float* __restrict__ bias,
                                                       float* __restrict__ pooled,
                                                       const int* __restrict__ batch, int n) {
    int node = (blockIdx.x * 256 + threadIdx.x) >> 6;
    int lane = threadIdx.x & 63;
    int es = lane >> 4;
    int fg = lane & 15;
    if (node >= n) return;

    int dg = degi[node];
    int de = dg - 1;
    float dn = 1.0f / sqrtf((float)dg);
    int start = row_start[node];

    float4 a0 = make_float4(0.f, 0.f, 0.f, 0.f);
    float4 a1 = a0, a2 = a0, a3 = a0;
    if (es == 0) a0 = *(const float4*)(g + (size_t)node * 64 + fg * 4);  // self-loop

    for (int c = 0; c < de; c += 64) {
        int m = min(64, de - c);
        int sv = (lane < m) ? csr_src[start + c + lane] : -1;
        int t = 0;
        for (; t + 16 <= m; t += 16) {
            int s0 = __shfl(sv, t + es);
            int s1 = __shfl(sv, t + 4 + es);
            int s2 = __shfl(sv, t + 8 + es);
            int s3 = __shfl(sv, t + 12 + es);
            float4 v0 = *(const float4*)(g + (size_t)s0 * 64 + fg * 4);
            float4 v1 = *(const float4*)(g + (size_t)s1 * 64 + fg * 4);
            float4 v2 = *(const float4*)(g + (size_t)s2 * 64 + fg * 4);
            float4 v3 = *(const float4*)(g + (size_t)s3 * 64 + fg * 4);
            a0.x += v0.x; a0.y += v0.y; a0.z += v0.z; a0.w += v0.w;
            a1.x += v1.x; a1.y += v1.y; a1.z += v1.z; a1.w += v1.w;
            a2.x += v2.x; a2.y += v2.y; a2.z += v2.z; a2.w += v2.w;
            a3.x += v3.x; a3.y += v3.y; a3.z += v3.z; a3.w += v3.w;
        }
        for (; t < m; t += 4) {
            int e = t + es;
            int s = __shfl(sv, e);
            if (e < m) {
                float4 v = *(const float4*)(g + (size_t)s * 64 + fg * 4);
                a0.x += v.x; a0.y += v.y; a0.z += v.z; a0.w += v.w;
            }
        }
    }
    float4 a;
    a.x = (a0.x + a1.x) + (a2.x + a3.x);
    a.y = (a0.y + a1.y) + (a2.y + a3.y);
    a.z = (a0.z + a1.z) + (a2.z + a3.z);
    a.w = (a0.w + a1.w) + (a2.w + a3.w);
    a.x += __shfl_xor(a.x, 16); a.y += __shfl_xor(a.y, 16);
    a.z += __shfl_xor(a.z, 16); a.w += __shfl_xor(a.w, 16);
    a.x += __shfl_xor(a.x, 32); a.y += __shfl_xor(a.y, 32);
    a.z += __shfl_xor(a.z, 32); a.w += __shfl_xor(a.w, 32);

    if (es == 0) {
        float4 bv = *(const float4*)(bias + fg * 4);
        float4 o;
        o.x = fmaf(dn, a.x, bv.x);
        o.y = fmaf(dn, a.y, bv.y);
        o.z = fmaf(dn, a.z, bv.z);
        o.w = fmaf(dn, a.w, bv.w);
        float* pp = pooled + (size_t)batch[node] * 64 + fg * 4;
        atomicAdd(pp + 0, o.x);
        atomicAdd(pp + 1, o.y);
        atomicAdd(pp + 2, o.z);
        atomicAdd(pp + 3, o.w);
    }
}

// ---------------------------------------------------------------- final FC, wave per graph
__global__ __launch_bounds__(256) void final_fc(const float* __restrict__ pooled,
                                                const int* __restrict__ cntg,
                                                const float* __restrict__ fc_w,
                                                const float* __restrict__ fc_b,
                                                float* __restrict__ out, int g) {
    int gid = (blockIdx.x * 256 + threadIdx.x) >> 6;
    int lane = threadIdx.x & 63;
    if (gid >= g) return;
    float c = fmaxf((float)cntg[gid], 1.0f);
    float v = pooled[(size_t)gid * 64 + lane] / c * fc_w[lane];
#pragma unroll
    for (int off = 32; off > 0; off >>= 1) v += __shfl_down(v, off);
    if (lane == 0) out[gid] = v + fc_b[0];
}

// ---------------------------------------------------------------- launch
extern "C" void kernel_launch(void* const* d_in, const int* in_sizes, int n_in,
                              void* d_out, int out_size, void* d_ws, size_t ws_size,
                              hipStream_t stream) {
    const float* x    = (const float*)d_in[0];
    const int*   eidx = (const int*)d_in[1];     // [2, E] flat: src row then dst row
    const int*   batch= (const int*)d_in[2];
    const float* W1   = (const float*)d_in[4];
    const float* b1   = (const float*)d_in[5];
    const float* W2   = (const float*)d_in[6];
    const float* b2   = (const float*)d_in[7];
    const float* fc_w = (const float*)d_in[8];
    const float* fc_b = (const float*)d_in[9];
    float* out = (float*)d_out;

    const int N = in_sizes[0] / IN_FEAT;
    const int E = in_sizes[1] / 2;
    const int G = N_GRAPHS;
    const int* src = eidx;
    const int* dst = eidx + E;
    const int nb = (N + NPB - 1) >> BSH;         // 391 buckets

    // workspace carve (all chunks 16B-aligned)
    char* w = (char*)d_ws;
    unsigned short* g1b = (unsigned short*)w; w += (size_t)N * 64 * 2;  // bf16 dinv*(x@W1)
    float* g2   = (float*)w; w += (size_t)N * 64 * 4;       // dinv * (relu(conv1) @ W2)
    int*   degi = (int*)w;   w += (size_t)N * 4;
    int*   rowst= (int*)w;   w += (size_t)N * 4;
    int*   boff = (int*)w;   w += (NBK + 1) * 4 + 12;       // keep 16B alignment
    int*   tail = (int*)w;   w += NBK * 4;
    unsigned* packed = (unsigned*)w; w += (size_t)NBK * BCAP * 4;  // padded bucket files (20MB)
    int*   csrs = (int*)w;   w += (size_t)E * 4;            // compact CSR srcs
    float* pooled = (float*)w; w += (size_t)G * 64 * 4;
    int*   cntg = (int*)w;   w += (size_t)G * 4;
    short* w1hi = (short*)w; w += (size_t)IN_FEAT * 64 * 2;
    short* w1lo = (short*)w; w += (size_t)IN_FEAT * 64 * 2;

    fused_init<<<512, 256, 0, stream>>>(pooled, cntg, tail, batch, W1, w1hi, w1lo, N, G);
    bucket_scatter<<<(E + CH - 1) / CH, 256, 0, stream>>>(src, dst, tail, packed, E);
    bucket_scan<<<1, 512, 0, stream>>>(tail, boff, nb);
    bucket_csr<<<nb, 256, 0, stream>>>(packed, boff, csrs, rowst, degi, N);

    gemm_mfma<IN_FEAT><<<(N + 63) / 64, 256, 0, stream>>>(x, w1hi, w1lo, degi, g1b, N);
    gcn_gather_fuse<<<(N * 64 + 255) / 256, 256, 0, stream>>>(
        g1b, degi, rowst, csrs, b1, W2, g2, N);
    gcn_gather_pool<<<(N * 64 + 255) / 256, 256, 0, stream>>>(
        g2, degi, rowst, csrs, b2, pooled, batch, N);
    final_fc<<<(G * 64 + 255) / 256, 256, 0, stream>>>(pooled, cntg, fc_w, fc_b, out, G);
}